// Round 9
// baseline (792.171 us; speedup 1.0000x reference)
//
#include <hip/hip_runtime.h>
#include <cstddef>

#define T_LEN 200
#define BATCH 4096
#define EMBD  25
#define HD    25
#define WCNT  50000

__device__ __forceinline__ float frcp(float x) {
#if __has_builtin(__builtin_amdgcn_rcpf)
    return __builtin_amdgcn_rcpf(x);
#else
    return 1.0f / x;
#endif
}

__device__ __forceinline__ float fsig(float x) {
    float e = __expf(-x);
    return frcp(1.0f + e);
}
__device__ __forceinline__ float ftanh_(float x) {
    float e = __expf(-2.0f * x);
    return (1.0f - e) * frcp(1.0f + e);
}

__device__ __forceinline__ float bperm_f(int bpidx, float v) {
    return __int_as_float(__builtin_amdgcn_ds_bpermute(bpidx, __float_as_int(v)));
}

// embP layout: [dir][i][w][3] : embP[((dir*25+i)*WCNT + w)*3 + {r,z,n}]
//   = b_ih[g] + sum_j w_ih[g][j]*emb[w][j], g = i, 25+i, 50+i
// Thread = one word w; lanes coalesce over w. Weights are wave-uniform -> s_load.
// emb rows staged via LDS so global reads stay coalesced.
__global__ __launch_bounds__(256) void embp2_kernel(
    const float* __restrict__ emb,
    const float* __restrict__ w_ih_f, const float* __restrict__ b_ih_f,
    const float* __restrict__ w_ih_b, const float* __restrict__ b_ih_b,
    float* __restrict__ embP)
{
    __shared__ float esh[256 * EMBD];
    const int dir = blockIdx.y;
    const int w0  = blockIdx.x * 256;
    const int tid = threadIdx.x;

    for (int k = tid; k < 256 * EMBD; k += 256) {
        int g = w0 * EMBD + k;
        esh[k] = (g < WCNT * EMBD) ? emb[g] : 0.0f;
    }
    __syncthreads();

    const int w = w0 + tid;
    if (w >= WCNT) return;
    const float* wih = dir ? w_ih_b : w_ih_f;
    const float* bih = dir ? b_ih_b : b_ih_f;

    float er[EMBD];
    #pragma unroll
    for (int j = 0; j < EMBD; ++j) er[j] = esh[tid * EMBD + j];

    for (int i = 0; i < HD; ++i) {
        float a0 = bih[i], a1 = bih[HD + i], a2 = bih[2 * HD + i];
        #pragma unroll
        for (int j = 0; j < EMBD; ++j) {
            float x = er[j];
            a0 = fmaf(wih[(0 * HD + i) * EMBD + j], x, a0);
            a1 = fmaf(wih[(1 * HD + i) * EMBD + j], x, a1);
            a2 = fmaf(wih[(2 * HD + i) * EMBD + j], x, a2);
        }
        float* o = embP + (((size_t)dir * HD + i) * WCNT + w) * 3;
        o[0] = a0; o[1] = a1; o[2] = a2;
    }
}

// One chain (batch, dir) per 64-lane wave. lane = jh*32 + l; l<25 = h-dim,
// jh = which half of the j (dot-product) range this lane covers.
// Each lane holds only 13 w per gate (39 total) -> fits the 64-arch-VGPR
// allocation without AGPR shuttling. Halves combined via ds_bpermute(lane^32).
// dir/b/idx are wave-uniform -> scalar loads + scalar time walk.
__global__ __launch_bounds__(256) void gru3_kernel(
    const int*   __restrict__ input,
    const float* __restrict__ hidden,
    const float* __restrict__ w_hh_f, const float* __restrict__ b_hh_f,
    const float* __restrict__ w_hh_b, const float* __restrict__ b_hh_b,
    const float* __restrict__ embP,
    float* __restrict__ out)
{
    __shared__ float hsh[4][28];   // 112 B/chain, float4-aligned

    const int tid  = threadIdx.x;
    const int wid  = __builtin_amdgcn_readfirstlane(tid >> 6);  // wave-uniform
    const int lane = tid & 63;
    const int jh   = lane >> 5;
    const int l    = lane & 31;
    const int csub = l < 25 ? l : 0;
    const int chain = blockIdx.x * 4 + wid;
    const int b    = chain >> 1;
    const int dir  = chain & 1;

    const float* whh = dir ? w_hh_b : w_hh_f;
    const float* bhh = dir ? b_hh_b : b_hh_f;

    // 13 consecutive j-weights per gate for (i=csub, j in [jh*12, jh*12+12])
    const int jo = jh * 12;
    float wq0[13], wq1[13], wq2[13];
    #pragma unroll
    for (int k = 0; k < 13; ++k) {
        wq0[k] = whh[(0 * 25 + csub) * 25 + jo + k];
        wq1[k] = whh[(1 * 25 + csub) * 25 + jo + k];
        wq2[k] = whh[(2 * 25 + csub) * 25 + jo + k];
    }
    if (jh) { wq0[0] = 0.f; wq1[0] = 0.f; wq2[0] = 0.f; }  // j=12 owned by jh=0
    // bias baked into jh=0 partial only
    const float bh0 = jh ? 0.f : bhh[csub];
    const float bh1 = jh ? 0.f : bhh[25 + csub];
    const float bh2 = jh ? 0.f : bhh[50 + csub];

    float h0v = 0.f;
    if (l < 25) h0v = hidden[((size_t)dir * BATCH + b) * HD + l];
    if (jh == 0 && l < 25) hsh[wid][l] = h0v;
    __builtin_amdgcn_wave_barrier();

    const char* hb = (const char*)&hsh[wid][0] + jh * 48;

    // scalar time walk (uniform): t -> row index
    int t0 = dir ? (T_LEN - 1) : 0;
    int t1 = dir ? (T_LEN - 2) : 1;
    int si_c = input[t0 * BATCH + b];
    int si_n = input[t1 * BATCH + b];

    const float* dbase = embP + (size_t)dir * HD * WCNT * 3;
    const unsigned lane_off = (unsigned)csub * WCNT * 3;

    float3 xg;
    {
        const float* p = dbase + lane_off + (unsigned)si_c * 3;
        xg.x = p[0]; xg.y = p[1]; xg.z = p[2];
    }

    const int bpidx = (lane ^ 32) << 2;
    float hown = h0v;
    float ymax = -3.0e38f;

    #pragma unroll 2
    for (int tt = 0; tt < T_LEN; ++tt) {
        // prefetch: gather for t+1, scalar idx for t+2
        float3 xgn;
        {
            const float* p = dbase + lane_off + (unsigned)si_n * 3;
            xgn.x = p[0]; xgn.y = p[1]; xgn.z = p[2];
        }
        int tpre = (tt + 2 < T_LEN) ? tt + 2 : T_LEN - 1;
        int trow = dir ? (T_LEN - 1 - tpre) : tpre;
        int si_n2 = input[trow * BATCH + b];

        float4 hv0 = *(const float4*)(hb);
        float4 hv1 = *(const float4*)(hb + 16);
        float4 hv2 = *(const float4*)(hb + 32);
        float h12  = *(const float*)(hb + 48);

        float ar = bh0, az = bh1, an = bh2;
        ar = fmaf(wq0[0], hv0.x, ar); az = fmaf(wq1[0], hv0.x, az); an = fmaf(wq2[0], hv0.x, an);
        ar = fmaf(wq0[1], hv0.y, ar); az = fmaf(wq1[1], hv0.y, az); an = fmaf(wq2[1], hv0.y, an);
        ar = fmaf(wq0[2], hv0.z, ar); az = fmaf(wq1[2], hv0.z, az); an = fmaf(wq2[2], hv0.z, an);
        ar = fmaf(wq0[3], hv0.w, ar); az = fmaf(wq1[3], hv0.w, az); an = fmaf(wq2[3], hv0.w, an);
        ar = fmaf(wq0[4], hv1.x, ar); az = fmaf(wq1[4], hv1.x, az); an = fmaf(wq2[4], hv1.x, an);
        ar = fmaf(wq0[5], hv1.y, ar); az = fmaf(wq1[5], hv1.y, az); an = fmaf(wq2[5], hv1.y, an);
        ar = fmaf(wq0[6], hv1.z, ar); az = fmaf(wq1[6], hv1.z, az); an = fmaf(wq2[6], hv1.z, an);
        ar = fmaf(wq0[7], hv1.w, ar); az = fmaf(wq1[7], hv1.w, az); an = fmaf(wq2[7], hv1.w, an);
        ar = fmaf(wq0[8], hv2.x, ar); az = fmaf(wq1[8], hv2.x, az); an = fmaf(wq2[8], hv2.x, an);
        ar = fmaf(wq0[9], hv2.y, ar); az = fmaf(wq1[9], hv2.y, az); an = fmaf(wq2[9], hv2.y, an);
        ar = fmaf(wq0[10], hv2.z, ar); az = fmaf(wq1[10], hv2.z, az); an = fmaf(wq2[10], hv2.z, an);
        ar = fmaf(wq0[11], hv2.w, ar); az = fmaf(wq1[11], hv2.w, az); an = fmaf(wq2[11], hv2.w, an);
        ar = fmaf(wq0[12], h12, ar);  az = fmaf(wq1[12], h12, az);  an = fmaf(wq2[12], h12, an);

        // combine the two j-halves (lane <-> lane^32)
        ar += bperm_f(bpidx, ar);
        az += bperm_f(bpidx, az);
        an += bperm_f(bpidx, an);

        float r = fsig(xg.x + ar);
        float z = fsig(xg.y + az);
        float n = ftanh_(fmaf(r, an, xg.z));
        float hnew = fmaf(z, hown - n, n);
        ymax = fmaxf(ymax, hnew);

        __builtin_amdgcn_wave_barrier();
        if (jh == 0 && l < 25) hsh[wid][l] = hnew;  // in-order per-wave DS
        __builtin_amdgcn_wave_barrier();

        hown = hnew;
        xg = xgn;
        si_n = si_n2;
    }

    if (jh == 0 && l < 25) {
        out[(size_t)b * 50 + dir * 25 + l] = ymax;                   // y = max over t
        out[204800 + ((size_t)dir * BATCH + b) * HD + l] = hown;     // final hidden
    }
}

// Fallback (no workspace): computes xg on the fly. (Round-1 kernel, passing.)
__global__ __launch_bounds__(256) void gru_fallback_kernel(
    const int*   __restrict__ input,
    const float* __restrict__ hidden,
    const float* __restrict__ emb,
    const float* __restrict__ w_hh_f, const float* __restrict__ b_hh_f,
    const float* __restrict__ w_ih_f, const float* __restrict__ b_ih_f,
    const float* __restrict__ w_hh_b, const float* __restrict__ b_hh_b,
    const float* __restrict__ w_ih_b, const float* __restrict__ b_ih_b,
    float* __restrict__ out)
{
    __shared__ float4 hsh4[8][7];
    __shared__ float4 xsh4[8][7];
    float* hshf = (float*)hsh4;
    float* xshf = (float*)xsh4;

    const int wave = threadIdx.x >> 6;
    const int half = (threadIdx.x >> 5) & 1;
    const int sub  = threadIdx.x & 31;
    const int b    = blockIdx.x * 4 + wave;
    const int dir  = half;
    const int csub = sub < 25 ? sub : 0;
    const int c    = wave * 2 + half;

    const float* whh = dir ? w_hh_b : w_hh_f;
    const float* bhh = dir ? b_hh_b : b_hh_f;
    const float* wih = dir ? w_ih_b : w_ih_f;
    const float* bih = dir ? b_ih_b : b_ih_f;

    float wg0[28], wg1[28], wg2[28], wi0[28], wi1[28], wi2[28];
    #pragma unroll
    for (int j = 0; j < 28; ++j) {
        wg0[j] = (j < 25) ? whh[(0 * 25 + csub) * 25 + j] : 0.0f;
        wg1[j] = (j < 25) ? whh[(1 * 25 + csub) * 25 + j] : 0.0f;
        wg2[j] = (j < 25) ? whh[(2 * 25 + csub) * 25 + j] : 0.0f;
        wi0[j] = (j < 25) ? wih[(0 * 25 + csub) * 25 + j] : 0.0f;
        wi1[j] = (j < 25) ? wih[(1 * 25 + csub) * 25 + j] : 0.0f;
        wi2[j] = (j < 25) ? wih[(2 * 25 + csub) * 25 + j] : 0.0f;
    }
    const float bh0 = bhh[csub], bh1 = bhh[25 + csub], bh2 = bhh[50 + csub];
    const float bx0 = bih[csub], bx1 = bih[25 + csub], bx2 = bih[50 + csub];

    float h0 = 0.0f;
    if (sub < 25) h0 = hidden[((size_t)dir * BATCH + b) * HD + sub];
    if (sub < 28) hshf[c * 28 + sub] = (sub < 25) ? h0 : 0.0f;
    if (sub >= 25 && sub < 28) xshf[c * 28 + sub] = 0.0f;
    __syncthreads();

    const int* ipt  = input + (dir ? (T_LEN - 1) * BATCH : 0) + b;
    const int  istr = dir ? -BATCH : BATCH;

    int idx_c = ipt[0];
    int idx_n = ipt[istr];
    float xcur = emb[(size_t)idx_c * EMBD + csub];

    float hown = h0;
    float ymax = -3.0e38f;

    for (int tt = 0; tt < T_LEN; ++tt) {
        int t2 = (tt + 2 < T_LEN) ? tt + 2 : T_LEN - 1;
        int idx_n2 = ipt[t2 * istr];
        float xnext = emb[(size_t)idx_n * EMBD + csub];
        __builtin_amdgcn_wave_barrier();
        if (sub < 25) xshf[c * 28 + sub] = xcur;
        __builtin_amdgcn_wave_barrier();

        float ar = bh0, az = bh1, an = bh2;
        float axr = bx0, axz = bx1, axn = bx2;
        #pragma unroll
        for (int jb = 0; jb < 7; ++jb) {
            float4 hv = hsh4[c][jb];
            float4 xv = xsh4[c][jb];
            ar = fmaf(wg0[4*jb+0], hv.x, ar); ar = fmaf(wg0[4*jb+1], hv.y, ar);
            ar = fmaf(wg0[4*jb+2], hv.z, ar); ar = fmaf(wg0[4*jb+3], hv.w, ar);
            az = fmaf(wg1[4*jb+0], hv.x, az); az = fmaf(wg1[4*jb+1], hv.y, az);
            az = fmaf(wg1[4*jb+2], hv.z, az); az = fmaf(wg1[4*jb+3], hv.w, az);
            an = fmaf(wg2[4*jb+0], hv.x, an); an = fmaf(wg2[4*jb+1], hv.y, an);
            an = fmaf(wg2[4*jb+2], hv.z, an); an = fmaf(wg2[4*jb+3], hv.w, an);
            axr = fmaf(wi0[4*jb+0], xv.x, axr); axr = fmaf(wi0[4*jb+1], xv.y, axr);
            axr = fmaf(wi0[4*jb+2], xv.z, axr); axr = fmaf(wi0[4*jb+3], xv.w, axr);
            axz = fmaf(wi1[4*jb+0], xv.x, axz); axz = fmaf(wi1[4*jb+1], xv.y, axz);
            axz = fmaf(wi1[4*jb+2], xv.z, axz); axz = fmaf(wi1[4*jb+3], xv.w, axz);
            axn = fmaf(wi2[4*jb+0], xv.x, axn); axn = fmaf(wi2[4*jb+1], xv.y, axn);
            axn = fmaf(wi2[4*jb+2], xv.z, axn); axn = fmaf(wi2[4*jb+3], xv.w, axn);
        }

        float r = fsig(axr + ar);
        float z = fsig(axz + az);
        float n = ftanh_(fmaf(r, an, axn));
        float hnew = fmaf(z, hown - n, n);
        ymax = fmaxf(ymax, hnew);

        __builtin_amdgcn_wave_barrier();
        if (sub < 25) hshf[c * 28 + sub] = hnew;
        __builtin_amdgcn_wave_barrier();

        hown = hnew;
        xcur = xnext;
        idx_c = idx_n; idx_n = idx_n2;
    }

    if (sub < 25) {
        out[(size_t)b * 50 + dir * 25 + sub] = ymax;
        out[204800 + ((size_t)dir * BATCH + b) * HD + sub] = hown;
    }
}

extern "C" void kernel_launch(void* const* d_in, const int* in_sizes, int n_in,
                              void* d_out, int out_size, void* d_ws, size_t ws_size,
                              hipStream_t stream) {
    const int*   input  = (const int*)  d_in[0];
    const float* hidden = (const float*)d_in[1];
    const float* emb    = (const float*)d_in[2];
    const float* w_ih_f = (const float*)d_in[3];
    const float* w_hh_f = (const float*)d_in[4];
    const float* b_ih_f = (const float*)d_in[5];
    const float* b_hh_f = (const float*)d_in[6];
    const float* w_ih_b = (const float*)d_in[7];
    const float* w_hh_b = (const float*)d_in[8];
    const float* b_ih_b = (const float*)d_in[9];
    const float* b_hh_b = (const float*)d_in[10];
    float* out = (float*)d_out;

    const size_t embp_bytes = (size_t)2 * HD * WCNT * 3 * sizeof(float);  // 30 MB
    if (ws_size >= embp_bytes) {
        float* embP = (float*)d_ws;
        dim3 grid((WCNT + 255) / 256, 2);
        embp2_kernel<<<grid, 256, 0, stream>>>(
            emb, w_ih_f, b_ih_f, w_ih_b, b_ih_b, embP);
        gru3_kernel<<<(2 * BATCH) / 4, 256, 0, stream>>>(
            input, hidden,
            w_hh_f, b_hh_f, w_hh_b, b_hh_b,
            embP, out);
    } else {
        gru_fallback_kernel<<<BATCH / 4, 256, 0, stream>>>(
            input, hidden, emb,
            w_hh_f, b_hh_f, w_ih_f, b_ih_f,
            w_hh_b, b_hh_b, w_ih_b, b_ih_b,
            out);
    }
}

// Round 12
// 337.868 us; speedup vs baseline: 2.3446x; 2.3446x over previous
//
#include <hip/hip_runtime.h>
#include <cstddef>

#define T_LEN 200
#define BATCH 4096
#define EMBD  25
#define HD    25
#define WCNT  50000

__device__ __forceinline__ float frcp(float x) {
#if __has_builtin(__builtin_amdgcn_rcpf)
    return __builtin_amdgcn_rcpf(x);
#else
    return 1.0f / x;
#endif
}

__device__ __forceinline__ float fsig(float x) {
    float e = __expf(-x);
    return frcp(1.0f + e);
}
__device__ __forceinline__ float ftanh_(float x) {
    float e = __expf(-2.0f * x);
    return (1.0f - e) * frcp(1.0f + e);
}

__device__ __forceinline__ float bperm_f(int bpidx, float v) {
    return __int_as_float(__builtin_amdgcn_ds_bpermute(bpidx, __float_as_int(v)));
}

// embP layout (ROW-CONTIGUOUS, round-2 proven): embP[(dir*WCNT + w)*75 + i*3 + {r,z,n}]
//   = b_ih[g] + sum_j w_ih[g][j]*emb[w][j], g = i, 25+i, 50+i
// A wave's 25 lanes read i*3..i*3+2 -> one contiguous 300B block per word.
__global__ __launch_bounds__(256) void embp2_kernel(
    const float* __restrict__ emb,
    const float* __restrict__ w_ih_f, const float* __restrict__ b_ih_f,
    const float* __restrict__ w_ih_b, const float* __restrict__ b_ih_b,
    float* __restrict__ embP)
{
    __shared__ float esh[256 * EMBD];
    const int dir = blockIdx.y;
    const int w0  = blockIdx.x * 256;
    const int tid = threadIdx.x;

    for (int k = tid; k < 256 * EMBD; k += 256) {
        int g = w0 * EMBD + k;
        esh[k] = (g < WCNT * EMBD) ? emb[g] : 0.0f;
    }
    __syncthreads();

    const int w = w0 + tid;
    if (w >= WCNT) return;
    const float* wih = dir ? w_ih_b : w_ih_f;
    const float* bih = dir ? b_ih_b : b_ih_f;

    float er[EMBD];
    #pragma unroll
    for (int j = 0; j < EMBD; ++j) er[j] = esh[tid * EMBD + j];

    float* orow = embP + ((size_t)dir * WCNT + w) * 75;
    for (int i = 0; i < HD; ++i) {
        float a0 = bih[i], a1 = bih[HD + i], a2 = bih[2 * HD + i];
        #pragma unroll
        for (int j = 0; j < EMBD; ++j) {
            float x = er[j];
            a0 = fmaf(wih[(0 * HD + i) * EMBD + j], x, a0);
            a1 = fmaf(wih[(1 * HD + i) * EMBD + j], x, a1);
            a2 = fmaf(wih[(2 * HD + i) * EMBD + j], x, a2);
        }
        orow[i * 3 + 0] = a0;
        orow[i * 3 + 1] = a1;
        orow[i * 3 + 2] = a2;
    }
}

// One chain (batch, dir) per 64-lane wave. lane = jh*32 + l; l<25 = h-dim,
// jh = which half of the j (dot-product) range this lane covers.
// 39 weights/lane -> fits the 64-VGPR allocation cleanly (round-9: VGPR=36,
// no AGPR shuttle). Halves combined via ds_bpermute(lane^32).
// Gather reads the row-contiguous embP (round-9's transposed layout was the
// 2.4GB-FETCH / HBM-bound mistake; this restores 300B-contiguous gathers).
__global__ __launch_bounds__(256) void gru3_kernel(
    const int*   __restrict__ input,
    const float* __restrict__ hidden,
    const float* __restrict__ w_hh_f, const float* __restrict__ b_hh_f,
    const float* __restrict__ w_hh_b, const float* __restrict__ b_hh_b,
    const float* __restrict__ embP,
    float* __restrict__ out)
{
    __shared__ float hsh[4][28];   // 112 B/chain, float4-aligned

    const int tid  = threadIdx.x;
    const int wid  = __builtin_amdgcn_readfirstlane(tid >> 6);  // wave-uniform
    const int lane = tid & 63;
    const int jh   = lane >> 5;
    const int l    = lane & 31;
    const int csub = l < 25 ? l : 0;
    const int chain = blockIdx.x * 4 + wid;
    const int b    = chain >> 1;
    const int dir  = chain & 1;

    const float* whh = dir ? w_hh_b : w_hh_f;
    const float* bhh = dir ? b_hh_b : b_hh_f;

    // 13 consecutive j-weights per gate for (i=csub, j in [jh*12, jh*12+12])
    const int jo = jh * 12;
    float wq0[13], wq1[13], wq2[13];
    #pragma unroll
    for (int k = 0; k < 13; ++k) {
        wq0[k] = whh[(0 * 25 + csub) * 25 + jo + k];
        wq1[k] = whh[(1 * 25 + csub) * 25 + jo + k];
        wq2[k] = whh[(2 * 25 + csub) * 25 + jo + k];
    }
    if (jh) { wq0[0] = 0.f; wq1[0] = 0.f; wq2[0] = 0.f; }  // j=12 owned by jh=0
    // bias baked into jh=0 partial only
    const float bh0 = jh ? 0.f : bhh[csub];
    const float bh1 = jh ? 0.f : bhh[25 + csub];
    const float bh2 = jh ? 0.f : bhh[50 + csub];

    float h0v = 0.f;
    if (l < 25) h0v = hidden[((size_t)dir * BATCH + b) * HD + l];
    if (jh == 0 && l < 25) hsh[wid][l] = h0v;
    __builtin_amdgcn_wave_barrier();

    const char* hb = (const char*)&hsh[wid][0] + jh * 48;

    // scalar time walk (uniform): t -> row index
    int t0 = dir ? (T_LEN - 1) : 0;
    int t1 = dir ? (T_LEN - 2) : 1;
    int si_c = input[t0 * BATCH + b];
    int si_n = input[t1 * BATCH + b];

    const float* tbl = embP + (size_t)dir * WCNT * 75;
    const unsigned lane_off = (unsigned)csub * 3;

    float3 xg;
    {
        const float* p = tbl + (size_t)si_c * 75 + lane_off;
        xg.x = p[0]; xg.y = p[1]; xg.z = p[2];
    }

    const int bpidx = (lane ^ 32) << 2;
    float hown = h0v;
    float ymax = -3.0e38f;

    #pragma unroll 2
    for (int tt = 0; tt < T_LEN; ++tt) {
        // prefetch: gather for t+1, scalar idx for t+2
        float3 xgn;
        {
            const float* p = tbl + (size_t)si_n * 75 + lane_off;
            xgn.x = p[0]; xgn.y = p[1]; xgn.z = p[2];
        }
        int tpre = (tt + 2 < T_LEN) ? tt + 2 : T_LEN - 1;
        int trow = dir ? (T_LEN - 1 - tpre) : tpre;
        int si_n2 = input[trow * BATCH + b];

        float4 hv0 = *(const float4*)(hb);
        float4 hv1 = *(const float4*)(hb + 16);
        float4 hv2 = *(const float4*)(hb + 32);
        float h12  = *(const float*)(hb + 48);

        float ar = bh0, az = bh1, an = bh2;
        ar = fmaf(wq0[0], hv0.x, ar); az = fmaf(wq1[0], hv0.x, az); an = fmaf(wq2[0], hv0.x, an);
        ar = fmaf(wq0[1], hv0.y, ar); az = fmaf(wq1[1], hv0.y, az); an = fmaf(wq2[1], hv0.y, an);
        ar = fmaf(wq0[2], hv0.z, ar); az = fmaf(wq1[2], hv0.z, az); an = fmaf(wq2[2], hv0.z, an);
        ar = fmaf(wq0[3], hv0.w, ar); az = fmaf(wq1[3], hv0.w, az); an = fmaf(wq2[3], hv0.w, an);
        ar = fmaf(wq0[4], hv1.x, ar); az = fmaf(wq1[4], hv1.x, az); an = fmaf(wq2[4], hv1.x, an);
        ar = fmaf(wq0[5], hv1.y, ar); az = fmaf(wq1[5], hv1.y, az); an = fmaf(wq2[5], hv1.y, an);
        ar = fmaf(wq0[6], hv1.z, ar); az = fmaf(wq1[6], hv1.z, az); an = fmaf(wq2[6], hv1.z, an);
        ar = fmaf(wq0[7], hv1.w, ar); az = fmaf(wq1[7], hv1.w, az); an = fmaf(wq2[7], hv1.w, an);
        ar = fmaf(wq0[8], hv2.x, ar); az = fmaf(wq1[8], hv2.x, az); an = fmaf(wq2[8], hv2.x, an);
        ar = fmaf(wq0[9], hv2.y, ar); az = fmaf(wq1[9], hv2.y, az); an = fmaf(wq2[9], hv2.y, an);
        ar = fmaf(wq0[10], hv2.z, ar); az = fmaf(wq1[10], hv2.z, az); an = fmaf(wq2[10], hv2.z, an);
        ar = fmaf(wq0[11], hv2.w, ar); az = fmaf(wq1[11], hv2.w, az); an = fmaf(wq2[11], hv2.w, an);
        ar = fmaf(wq0[12], h12, ar);  az = fmaf(wq1[12], h12, az);  an = fmaf(wq2[12], h12, an);

        // combine the two j-halves (lane <-> lane^32)
        ar += bperm_f(bpidx, ar);
        az += bperm_f(bpidx, az);
        an += bperm_f(bpidx, an);

        float r = fsig(xg.x + ar);
        float z = fsig(xg.y + az);
        float n = ftanh_(fmaf(r, an, xg.z));
        float hnew = fmaf(z, hown - n, n);
        ymax = fmaxf(ymax, hnew);

        __builtin_amdgcn_wave_barrier();
        if (jh == 0 && l < 25) hsh[wid][l] = hnew;  // in-order per-wave DS
        __builtin_amdgcn_wave_barrier();

        hown = hnew;
        xg = xgn;
        si_n = si_n2;
    }

    if (jh == 0 && l < 25) {
        out[(size_t)b * 50 + dir * 25 + l] = ymax;                   // y = max over t
        out[204800 + ((size_t)dir * BATCH + b) * HD + l] = hown;     // final hidden
    }
}

// Fallback (no workspace): computes xg on the fly. (Round-1 kernel, passing.)
__global__ __launch_bounds__(256) void gru_fallback_kernel(
    const int*   __restrict__ input,
    const float* __restrict__ hidden,
    const float* __restrict__ emb,
    const float* __restrict__ w_hh_f, const float* __restrict__ b_hh_f,
    const float* __restrict__ w_ih_f, const float* __restrict__ b_ih_f,
    const float* __restrict__ w_hh_b, const float* __restrict__ b_hh_b,
    const float* __restrict__ w_ih_b, const float* __restrict__ b_ih_b,
    float* __restrict__ out)
{
    __shared__ float4 hsh4[8][7];
    __shared__ float4 xsh4[8][7];
    float* hshf = (float*)hsh4;
    float* xshf = (float*)xsh4;

    const int wave = threadIdx.x >> 6;
    const int half = (threadIdx.x >> 5) & 1;
    const int sub  = threadIdx.x & 31;
    const int b    = blockIdx.x * 4 + wave;
    const int dir  = half;
    const int csub = sub < 25 ? sub : 0;
    const int c    = wave * 2 + half;

    const float* whh = dir ? w_hh_b : w_hh_f;
    const float* bhh = dir ? b_hh_b : b_hh_f;
    const float* wih = dir ? w_ih_b : w_ih_f;
    const float* bih = dir ? b_ih_b : b_ih_f;

    float wg0[28], wg1[28], wg2[28], wi0[28], wi1[28], wi2[28];
    #pragma unroll
    for (int j = 0; j < 28; ++j) {
        wg0[j] = (j < 25) ? whh[(0 * 25 + csub) * 25 + j] : 0.0f;
        wg1[j] = (j < 25) ? whh[(1 * 25 + csub) * 25 + j] : 0.0f;
        wg2[j] = (j < 25) ? whh[(2 * 25 + csub) * 25 + j] : 0.0f;
        wi0[j] = (j < 25) ? wih[(0 * 25 + csub) * 25 + j] : 0.0f;
        wi1[j] = (j < 25) ? wih[(1 * 25 + csub) * 25 + j] : 0.0f;
        wi2[j] = (j < 25) ? wih[(2 * 25 + csub) * 25 + j] : 0.0f;
    }
    const float bh0 = bhh[csub], bh1 = bhh[25 + csub], bh2 = bhh[50 + csub];
    const float bx0 = bih[csub], bx1 = bih[25 + csub], bx2 = bih[50 + csub];

    float h0 = 0.0f;
    if (sub < 25) h0 = hidden[((size_t)dir * BATCH + b) * HD + sub];
    if (sub < 28) hshf[c * 28 + sub] = (sub < 25) ? h0 : 0.0f;
    if (sub >= 25 && sub < 28) xshf[c * 28 + sub] = 0.0f;
    __syncthreads();

    const int* ipt  = input + (dir ? (T_LEN - 1) * BATCH : 0) + b;
    const int  istr = dir ? -BATCH : BATCH;

    int idx_c = ipt[0];
    int idx_n = ipt[istr];
    float xcur = emb[(size_t)idx_c * EMBD + csub];

    float hown = h0;
    float ymax = -3.0e38f;

    for (int tt = 0; tt < T_LEN; ++tt) {
        int t2 = (tt + 2 < T_LEN) ? tt + 2 : T_LEN - 1;
        int idx_n2 = ipt[t2 * istr];
        float xnext = emb[(size_t)idx_n * EMBD + csub];
        __builtin_amdgcn_wave_barrier();
        if (sub < 25) xshf[c * 28 + sub] = xcur;
        __builtin_amdgcn_wave_barrier();

        float ar = bh0, az = bh1, an = bh2;
        float axr = bx0, axz = bx1, axn = bx2;
        #pragma unroll
        for (int jb = 0; jb < 7; ++jb) {
            float4 hv = hsh4[c][jb];
            float4 xv = xsh4[c][jb];
            ar = fmaf(wg0[4*jb+0], hv.x, ar); ar = fmaf(wg0[4*jb+1], hv.y, ar);
            ar = fmaf(wg0[4*jb+2], hv.z, ar); ar = fmaf(wg0[4*jb+3], hv.w, ar);
            az = fmaf(wg1[4*jb+0], hv.x, az); az = fmaf(wg1[4*jb+1], hv.y, az);
            az = fmaf(wg1[4*jb+2], hv.z, az); az = fmaf(wg1[4*jb+3], hv.w, az);
            an = fmaf(wg2[4*jb+0], hv.x, an); an = fmaf(wg2[4*jb+1], hv.y, an);
            an = fmaf(wg2[4*jb+2], hv.z, an); an = fmaf(wg2[4*jb+3], hv.w, an);
            axr = fmaf(wi0[4*jb+0], xv.x, axr); axr = fmaf(wi0[4*jb+1], xv.y, axr);
            axr = fmaf(wi0[4*jb+2], xv.z, axr); axr = fmaf(wi0[4*jb+3], xv.w, axr);
            axz = fmaf(wi1[4*jb+0], xv.x, axz); axz = fmaf(wi1[4*jb+1], xv.y, axz);
            axz = fmaf(wi1[4*jb+2], xv.z, axz); axz = fmaf(wi1[4*jb+3], xv.w, axz);
            axn = fmaf(wi2[4*jb+0], xv.x, axn); axn = fmaf(wi2[4*jb+1], xv.y, axn);
            axn = fmaf(wi2[4*jb+2], xv.z, axn); axn = fmaf(wi2[4*jb+3], xv.w, axn);
        }

        float r = fsig(axr + ar);
        float z = fsig(axz + az);
        float n = ftanh_(fmaf(r, an, axn));
        float hnew = fmaf(z, hown - n, n);
        ymax = fmaxf(ymax, hnew);

        __builtin_amdgcn_wave_barrier();
        if (sub < 25) hshf[c * 28 + sub] = hnew;
        __builtin_amdgcn_wave_barrier();

        hown = hnew;
        xcur = xnext;
        idx_c = idx_n; idx_n = idx_n2;
    }

    if (sub < 25) {
        out[(size_t)b * 50 + dir * 25 + sub] = ymax;
        out[204800 + ((size_t)dir * BATCH + b) * HD + sub] = hown;
    }
}

extern "C" void kernel_launch(void* const* d_in, const int* in_sizes, int n_in,
                              void* d_out, int out_size, void* d_ws, size_t ws_size,
                              hipStream_t stream) {
    const int*   input  = (const int*)  d_in[0];
    const float* hidden = (const float*)d_in[1];
    const float* emb    = (const float*)d_in[2];
    const float* w_ih_f = (const float*)d_in[3];
    const float* w_hh_f = (const float*)d_in[4];
    const float* b_ih_f = (const float*)d_in[5];
    const float* b_hh_f = (const float*)d_in[6];
    const float* w_ih_b = (const float*)d_in[7];
    const float* w_hh_b = (const float*)d_in[8];
    const float* b_ih_b = (const float*)d_in[9];
    const float* b_hh_b = (const float*)d_in[10];
    float* out = (float*)d_out;

    const size_t embp_bytes = (size_t)2 * WCNT * 75 * sizeof(float);  // 30 MB
    if (ws_size >= embp_bytes) {
        float* embP = (float*)d_ws;
        dim3 grid((WCNT + 255) / 256, 2);
        embp2_kernel<<<grid, 256, 0, stream>>>(
            emb, w_ih_f, b_ih_f, w_ih_b, b_ih_b, embP);
        gru3_kernel<<<(2 * BATCH) / 4, 256, 0, stream>>>(
            input, hidden,
            w_hh_f, b_hh_f, w_hh_b, b_hh_b,
            embP, out);
    } else {
        gru_fallback_kernel<<<BATCH / 4, 256, 0, stream>>>(
            input, hidden, emb,
            w_hh_f, b_hh_f, w_ih_f, b_ih_f,
            w_hh_b, b_hh_b, w_ih_b, b_ih_b,
            out);
    }
}